// Round 4
// baseline (549.424 us; speedup 1.0000x reference)
//
#include <hip/hip_runtime.h>

#define HW 16384
#define NQ 300
#define NM 100
#define NB 8
#define NC 81
#define KCH 1024   // K split into 16 chunks
#define NKC 16
#define CTP 304    // padded leading dim for transposed cost

typedef __attribute__((ext_vector_type(8))) short frag8;
typedef __attribute__((ext_vector_type(4))) float float4v;
typedef __attribute__((ext_vector_type(4))) unsigned short ushort4v;

__device__ __forceinline__ unsigned short f2bf(float f) {
  union { float f; unsigned u; } c; c.f = f;
  unsigned r = c.u + 0x7FFFu + ((c.u >> 16) & 1u);
  return (unsigned short)(r >> 16);
}

// ---- prep: sigmoid(pred_masks)->bf16 + row sums; gt_masks->bf16 + row sums ----
__global__ __launch_bounds__(256) void prep_kernel(
    const float* __restrict__ pmask, const float* __restrict__ gmask,
    unsigned short* __restrict__ pm, unsigned short* __restrict__ gm,
    float* __restrict__ psum, float* __restrict__ gsum) {
  int row = blockIdx.x;            // 0..2399 = pm rows, 2400..3199 = gm rows
  int t = threadIdx.x;
  bool isP = row < NB * NQ;
  const float* srcf = isP ? (pmask + (size_t)row * HW)
                          : (gmask + (size_t)(row - NB * NQ) * HW);
  unsigned short* dst = isP ? (pm + (size_t)row * HW)
                            : (gm + (size_t)(row - NB * NQ) * HW);
  const float4v* src = (const float4v*)srcf;
  float s = 0.f;
  for (int i = t; i < HW / 4; i += 256) {
    float4v x = src[i];
    float y0, y1, y2, y3;
    if (isP) {
      y0 = 1.f / (1.f + __expf(-x.x));
      y1 = 1.f / (1.f + __expf(-x.y));
      y2 = 1.f / (1.f + __expf(-x.z));
      y3 = 1.f / (1.f + __expf(-x.w));
    } else { y0 = x.x; y1 = x.y; y2 = x.z; y3 = x.w; }
    s += (y0 + y1) + (y2 + y3);
    ushort4v o = { f2bf(y0), f2bf(y1), f2bf(y2), f2bf(y3) };
    *(ushort4v*)(dst + i * 4) = o;
  }
  for (int off = 32; off > 0; off >>= 1) s += __shfl_xor(s, off, 64);
  __shared__ float red[4];
  int wave = t >> 6, lane = t & 63;
  if (lane == 0) red[wave] = s;
  __syncthreads();
  if (t == 0) {
    float tot = (red[0] + red[1]) + (red[2] + red[3]);
    if (isP) psum[row] = tot; else gsum[row - NB * NQ] = tot;
  }
}

// ---- softmax over 81 classes, one wave per (b,q) row ----
__global__ __launch_bounds__(256) void softmax_kernel(
    const float* __restrict__ logits, float* __restrict__ probs) {
  int wave = threadIdx.x >> 6, lane = threadIdx.x & 63;
  int row = blockIdx.x * 4 + wave;          // < 2400 (grid=600)
  const float* in = logits + (size_t)row * NC;
  float x0 = (lane < NC) ? in[lane] : -1e30f;
  float x1 = (lane + 64 < NC) ? in[lane + 64] : -1e30f;
  float mx = fmaxf(x0, x1);
  for (int off = 32; off > 0; off >>= 1) mx = fmaxf(mx, __shfl_xor(mx, off, 64));
  float e0 = (lane < NC) ? __expf(x0 - mx) : 0.f;
  float e1 = (lane + 64 < NC) ? __expf(x1 - mx) : 0.f;
  float s = e0 + e1;
  for (int off = 32; off > 0; off >>= 1) s += __shfl_xor(s, off, 64);
  float inv = 1.f / s;
  if (lane < NC) probs[(size_t)row * NC + lane] = e0 * inv;
  if (lane + 64 < NC) probs[(size_t)row * NC + lane + 64] = e1 * inv;
}

// ---- bf16 MFMA batched GEMM: dot[b,q,m] accumulated via fp32 atomics ----
__global__ __launch_bounds__(64) void dot_kernel(
    const unsigned short* __restrict__ pm, const unsigned short* __restrict__ gm,
    float* __restrict__ dotv) {
  int qt = blockIdx.x;                      // 0..18 (16-q tiles)
  int b = blockIdx.y >> 4, kc = blockIdx.y & 15;
  int lane = threadIdx.x;
  int q0 = qt * 16;
  int row_a = q0 + (lane & 15);
  int ra = (row_a < NQ) ? row_a : NQ - 1;   // clamp; clamped rows never stored
  int koff = (lane >> 4) * 8;
  const unsigned short* pA = pm + ((size_t)b * NQ + ra) * HW + kc * KCH + koff;
  const unsigned short* pB0 = gm + (size_t)b * NM * HW + kc * KCH + koff;
  const unsigned short* pB[7];
#pragma unroll
  for (int mt = 0; mt < 7; ++mt) {
    int row_b = mt * 16 + (lane & 15);
    int rb = (row_b < NM) ? row_b : NM - 1;
    pB[mt] = pB0 + (size_t)rb * HW;
  }
  float4v acc[7];
#pragma unroll
  for (int mt = 0; mt < 7; ++mt) acc[mt] = (float4v){0.f, 0.f, 0.f, 0.f};
#pragma unroll 2
  for (int k = 0; k < KCH; k += 32) {
    frag8 a = *(const frag8*)(pA + k);
#pragma unroll
    for (int mt = 0; mt < 7; ++mt) {
      frag8 bb = *(const frag8*)(pB[mt] + k);
      acc[mt] = __builtin_amdgcn_mfma_f32_16x16x32_bf16(a, bb, acc[mt], 0, 0, 0);
    }
  }
  // C/D layout: col = lane&15 (m), row = (lane>>4)*4 + r (q)
#pragma unroll
  for (int mt = 0; mt < 7; ++mt) {
    int cm = mt * 16 + (lane & 15);
    if (cm < NM) {
#pragma unroll
      for (int r = 0; r < 4; ++r) {
        int cq = q0 + (lane >> 4) * 4 + r;
        if (cq < NQ)
          unsafeAtomicAdd(&dotv[((size_t)b * NQ + cq) * NM + cm], acc[mt][r]);
      }
    }
  }
}

// ---- combine all cost terms -> C (d_out) and transposed copy CT (ws) ----
__global__ __launch_bounds__(256) void combine_kernel(
    const float* __restrict__ dotv, const float* __restrict__ psum,
    const float* __restrict__ gsum, const float* __restrict__ probs,
    const int* __restrict__ labels, const float* __restrict__ pboxes,
    const float* __restrict__ gboxes, float* __restrict__ outC,
    float* __restrict__ ct) {
  int idx = blockIdx.x * 256 + threadIdx.x;
  if (idx >= NB * NQ * NM) return;
  int b = idx / (NQ * NM);
  int r = idx - b * (NQ * NM);
  int q = r / NM;
  int m = r - q * NM;
  float num = 2.f * dotv[idx];
  float den = psum[b * NQ + q] + gsum[b * NM + m];
  float cmask = 1.f - num / (den + 1e-6f);
  int lab = labels[b * NM + m];
  float cclass = -probs[((size_t)b * NQ + q) * NC + lab];
  const float* pb = pboxes + ((size_t)b * NQ + q) * 4;
  const float* gb = gboxes + ((size_t)b * NM + m) * 4;
  float p0 = pb[0], p1 = pb[1], p2 = pb[2], p3 = pb[3];
  float g0 = gb[0], g1 = gb[1], g2 = gb[2], g3 = gb[3];
  float cbbox = fabsf(p0 - g0) + fabsf(p1 - g1) + fabsf(p2 - g2) + fabsf(p3 - g3);
  float iw = fmaxf(fminf(p2, g2) - fmaxf(p0, g0), 0.f);
  float ih = fmaxf(fminf(p3, g3) - fmaxf(p1, g1), 0.f);
  float inter = iw * ih;
  float a1 = (p2 - p0) * (p3 - p1), a2 = (g2 - g0) * (g3 - g1);
  float uni = a1 + a2 - inter;
  float iou = inter / (uni + 1e-6f);
  float aw = fmaxf(fmaxf(p2, g2) - fminf(p0, g0), 0.f);
  float ah = fmaxf(fmaxf(p3, g3) - fminf(p1, g1), 0.f);
  float am = aw * ah;
  float giou = iou - (am - uni) / (am + 1e-6f);
  float C = cclass + 5.f * (cbbox - giou) + 2.f * cmask;
  outC[idx] = C;
  ct[((size_t)b * NM + m) * CTP + q] = C;   // transposed for the solver
}

// f32 full-wave min via DPP (row_shr 1/2/4/8 + bcast15/31 -> lane 63).
// old = x: invalid-source lanes min with self (harmless for a single min).
__device__ __forceinline__ float wave_fmin_bcast(float x) {
  int t;
  t = __builtin_amdgcn_update_dpp(__float_as_int(x), __float_as_int(x), 0x111, 0xf, 0xf, false);
  x = fminf(x, __int_as_float(t));
  t = __builtin_amdgcn_update_dpp(__float_as_int(x), __float_as_int(x), 0x112, 0xf, 0xf, false);
  x = fminf(x, __int_as_float(t));
  t = __builtin_amdgcn_update_dpp(__float_as_int(x), __float_as_int(x), 0x114, 0xf, 0xf, false);
  x = fminf(x, __int_as_float(t));
  t = __builtin_amdgcn_update_dpp(__float_as_int(x), __float_as_int(x), 0x118, 0xf, 0xf, false);
  x = fminf(x, __int_as_float(t));
  t = __builtin_amdgcn_update_dpp(__float_as_int(x), __float_as_int(x), 0x142, 0xf, 0xf, false);
  x = fminf(x, __int_as_float(t));
  t = __builtin_amdgcn_update_dpp(__float_as_int(x), __float_as_int(x), 0x143, 0xf, 0xf, false);
  x = fminf(x, __int_as_float(t));
  return __int_as_float(__builtin_amdgcn_readlane(__float_as_int(x), 63));
}

// (min1,min2) pair reduce over the wave. Pair-merge identity:
//   min1' = min(a1,b1); min2' = min(max(a1,b1), a2, b2)
// REQUIRES the incoming pair from invalid-source lanes to be (+INF,+INF):
// pass old = +INF to update_dpp (R3 bug: old = self duplicated the min into
// min2, making c2==m1g spuriously -> ARR "tie" -> rows leaked to SAP, +60us).
// Non-destination lanes of bcast steps likewise merge INF (no-op). Lane 63
// accumulates the exact top-2 of all 64 lanes; broadcast via readlane.
#define PAIR_STEP(PAT)                                                         \
  {                                                                            \
    int t1 = __builtin_amdgcn_update_dpp(0x7f800000, __float_as_int(m1), PAT, 0xf, 0xf, false); \
    int t2 = __builtin_amdgcn_update_dpp(0x7f800000, __float_as_int(m2), PAT, 0xf, 0xf, false); \
    float o1 = __int_as_float(t1), o2 = __int_as_float(t2);                    \
    float hi = fmaxf(m1, o1);                                                  \
    m1 = fminf(m1, o1);                                                        \
    m2 = fminf(fminf(m2, o2), hi);                                             \
  }
__device__ __forceinline__ void wave_fmin2_bcast(float m1, float m2,
                                                 float* g1, float* g2) {
  PAIR_STEP(0x111) PAIR_STEP(0x112) PAIR_STEP(0x114) PAIR_STEP(0x118)
  PAIR_STEP(0x142) PAIR_STEP(0x143)
  *g1 = __int_as_float(__builtin_amdgcn_readlane(__float_as_int(m1), 63));
  *g2 = __int_as_float(__builtin_amdgcn_readlane(__float_as_int(m2), 63));
}

// ---- Jonker-Volgenant on cost.T [100 x 300], one wave per batch ----
// v5 = v4 with the pair-reduce old-operand fix (see PAIR_STEP comment).
// Structure: greedy init + budgeted register-resident ARR + Dijkstra SAP.
extern __shared__ char hsmem[];
__global__ __launch_bounds__(64) void hungarian_kernel(
    const float* __restrict__ ct, float* __restrict__ out) {
  float* cost   = (float*)hsmem;                     // 100*304 f32 = 121600 B
  float* u      = (float*)(hsmem + 121600);          // 100 f32
  int*   p      = (int*)(hsmem + 122000);            // 320 int (col -> row)
  int*   way    = (int*)(hsmem + 123280);            // 320 int
  int*   colOwn = (int*)(hsmem + 124560);            // 320 int (reused: flist)
  int*   queue  = (int*)(hsmem + 125840);            // 320 int (init build only)
  int*   flist  = colOwn;                            // free-row list (<=100)
  const int b = blockIdx.x;
  const int lane = threadIdx.x;
  const float INF = __builtin_inff();

  // vectorized cost load: 121600 B as float4 (CTP=304 keeps rows 16B-aligned)
  {
    const float4v* a4 = (const float4v*)(ct + (size_t)b * NM * CTP);
    float4v* c4 = (float4v*)cost;
    for (int i = lane; i < NM * CTP / 4; i += 64) c4[i] = a4[i];
  }
#pragma unroll
  for (int w = 0; w < 5; ++w) {
    p[lane + 64 * w] = -1;
    colOwn[lane + 64 * w] = 0x7fffffff;
  }
  float v[5];
#pragma unroll
  for (int w = 0; w < 5; ++w) v[w] = 0.f;
  __syncthreads();

  // ---- row reduction with rotated column order (bank-conflict-free) ----
  // lane handles rows lane and lane+64; start offset o = (17*lane)&31 makes
  // bank = (lane + t) mod 32 => 2 lanes/bank (free). Lowest-col tie-break
  // keeps the argmin identical to an ascending scan.
  int rarg0 = 0, rarg1 = 0;
  {
    int o = (17 * lane) & 31;
    float mv0 = INF, mv1 = INF;
    int cj0 = 0x7fffffff, cj1 = 0x7fffffff;
    bool two = lane < NM - 64;
    for (int t = 0; t < CTP; ++t) {
      int jj = t + o; if (jj >= CTP) jj -= CTP;
      float c0 = cost[lane * CTP + jj];
      float c1 = two ? cost[(lane + 64) * CTP + jj] : 0.f;
      if (jj < NQ) {
        if (c0 < mv0 || (c0 == mv0 && jj < cj0)) { mv0 = c0; cj0 = jj; }
        if (two && (c1 < mv1 || (c1 == mv1 && jj < cj1))) { mv1 = c1; cj1 = jj; }
      }
    }
    u[lane] = mv0; rarg0 = cj0;
    if (two) { u[lane + 64] = mv1; rarg1 = cj1; }
  }
  // ---- parallel greedy: lowest row index wins its argmin column ----
  atomicMin(&colOwn[rarg0], lane);
  if (lane < NM - 64) atomicMin(&colOwn[rarg1], lane + 64);
  __syncthreads();
  unsigned long long ru0, ru1;   // rowUsed bitmasks (uniform)
  int free0, free1;
  {
    bool won0 = (colOwn[rarg0] == lane);
    if (won0) p[rarg0] = lane;
    free0 = won0 ? 0 : 1;
    bool won1 = (lane < NM - 64) && (colOwn[rarg1] == lane + 64);
    if (won1) p[rarg1] = lane + 64;
    free1 = ((lane < NM - 64) && !won1) ? 1 : 0;
    ru0 = __ballot(won0);
    ru1 = __ballot(won1);
  }
  // deterministic free-row queue, ascending row index (LDS build, one-time)
  int qt_;   // tail
  {
    unsigned long long m0 = __ballot(free0 != 0);
    if (free0) queue[__popcll(m0 & ((1ull << lane) - 1ull))] = lane;
    int base = (int)__popcll(m0);
    unsigned long long m1 = __ballot(free1 != 0);
    if (free1) queue[base + (int)__popcll(m1 & ((1ull << lane) - 1ull))] = lane + 64;
    qt_ = base + (int)__popcll(m1);
  }
  __syncthreads();
  // register mirrors: queue and p (constant-indexed only; rule #20)
  int q0 = queue[lane], q1 = queue[lane + 64], q2 = queue[lane + 128],
      q3 = queue[lane + 192], q4 = queue[lane + 256];
  int pr0 = p[lane], pr1 = p[lane + 64], pr2 = p[lane + 128],
      pr3 = p[lane + 192], pr4 = p[lane + 256];

#define QREAD(pos, dst)                                                  \
  { int _w = (pos) >> 6, _l = (pos) & 63;                                \
    if (_w == 0)      dst = __builtin_amdgcn_readlane(q0, _l);           \
    else if (_w == 1) dst = __builtin_amdgcn_readlane(q1, _l);           \
    else if (_w == 2) dst = __builtin_amdgcn_readlane(q2, _l);           \
    else if (_w == 3) dst = __builtin_amdgcn_readlane(q3, _l);           \
    else              dst = __builtin_amdgcn_readlane(q4, _l); }
#define QWRITE(pos, val)                                                 \
  { int _w = (pos) >> 6, _l = (pos) & 63;                                \
    if (_w == 0)      { if (lane == _l) q0 = (val); }                    \
    else if (_w == 1) { if (lane == _l) q1 = (val); }                    \
    else if (_w == 2) { if (lane == _l) q2 = (val); }                    \
    else if (_w == 3) { if (lane == _l) q3 = (val); }                    \
    else              { if (lane == _l) q4 = (val); } }
#define PREAD(pos, dst)                                                  \
  { int _w = (pos) >> 6, _l = (pos) & 63;                                \
    if (_w == 0)      dst = __builtin_amdgcn_readlane(pr0, _l);          \
    else if (_w == 1) dst = __builtin_amdgcn_readlane(pr1, _l);          \
    else if (_w == 2) dst = __builtin_amdgcn_readlane(pr2, _l);          \
    else if (_w == 3) dst = __builtin_amdgcn_readlane(pr3, _l);          \
    else              dst = __builtin_amdgcn_readlane(pr4, _l); }
#define PWRITE(pos, val)                                                 \
  { int _w = (pos) >> 6, _l = (pos) & 63;                                \
    if (_w == 0)      { if (lane == _l) pr0 = (val); }                   \
    else if (_w == 1) { if (lane == _l) pr1 = (val); }                   \
    else if (_w == 2) { if (lane == _l) pr2 = (val); }                   \
    else if (_w == 3) { if (lane == _l) pr3 = (val); }                   \
    else              { if (lane == _l) pr4 = (val); } }

  float pf0 = 0.f, pf1 = 0.f, pf2 = 0.f, pf3 = 0.f, pf4 = 0.f;
  int pfrow = -1;
  int j4c = lane + 256; if (j4c > 303) j4c = 303;   // clamp (masked later)
#define PFETCH(r)                                                        \
  { int _base = (r) * CTP;                                               \
    pf0 = cost[_base + lane];        pf1 = cost[_base + lane + 64];      \
    pf2 = cost[_base + lane + 128];  pf3 = cost[_base + lane + 192];     \
    pf4 = cost[_base + j4c];         pfrow = (r); }

  // ---- augmenting row reduction (budgeted), fully register-resident ----
  {
    int h = 0, tl = qt_, pops = 0;
    int nexti = -1;
    if (h < tl) { QREAD(h, nexti); PFETCH(nexti); }
    while (nexti >= 0 && pops < 192) {
      int i = nexti; ++h; ++pops;
      if (pfrow != i) PFETCH(i);                 // safety (never in practice)
      // reduced costs from prefetched row; per-lane (min1,min2)
      float t0 = pf0 - v[0];
      float t1 = pf1 - v[1];
      float t2 = pf2 - v[2];
      float t3 = pf3 - v[3];
      float t4 = (lane + 256 < NQ) ? (pf4 - v[4]) : INF;
      float m1 = INF, m2 = INF;
#define INS(x) { if ((x) < m1) { m2 = m1; m1 = (x); } else if ((x) < m2) m2 = (x); }
      INS(t0) INS(t1) INS(t2) INS(t3) INS(t4)
#undef INS
      // prefetch next queued row while the reduce runs
      nexti = -1;
      if (h < tl) { QREAD(h, nexti); PFETCH(nexti); }
      float m1g, c2;
      wave_fmin2_bcast(m1, m2, &m1g, &c2);
      int j1 = -1;
      {
        unsigned long long mk;
        mk = __ballot(t0 == m1g); if (mk) j1 = (int)__builtin_ctzll(mk);
        if (j1 < 0) { mk = __ballot(t1 == m1g); if (mk) j1 = (int)__builtin_ctzll(mk) + 64; }
        if (j1 < 0) { mk = __ballot(t2 == m1g); if (mk) j1 = (int)__builtin_ctzll(mk) + 128; }
        if (j1 < 0) { mk = __ballot(t3 == m1g); if (mk) j1 = (int)__builtin_ctzll(mk) + 192; }
        if (j1 < 0) { mk = __ballot(t4 == m1g); if (mk) j1 = (int)__builtin_ctzll(mk) + 256; }
      }
      float delta = (c2 > m1g) ? (c2 - m1g) : 0.f;
      int i1; PREAD(j1, i1);
      if (i1 >= 0 && delta <= 0.f) {
        // exact tie on an occupied column: leave row i free for SAP
        if (lane == 0) u[i] = c2;
        continue;
      }
#pragma unroll
      for (int w = 0; w < 5; ++w) if (lane + 64 * w == j1) v[w] -= delta;
      if (lane == 0) u[i] = c2;
      PWRITE(j1, i);
      if (i < 64) ru0 |= 1ull << i; else ru1 |= 1ull << (i - 64);
      if (i1 >= 0) {
        if (i1 < 64) ru0 &= ~(1ull << i1); else ru1 &= ~(1ull << (i1 - 64));
        QWRITE(tl, i1); ++tl;
        if (nexti < 0) { nexti = i1; PFETCH(i1); }
      }
    }
  }
  // write mirrors back for SAP/emit
  p[lane] = pr0; p[lane + 64] = pr1; p[lane + 128] = pr2;
  p[lane + 192] = pr3; p[lane + 256] = pr4;
  __syncthreads();

  // ---- collect free rows from masks (SAP never frees an assigned row) ----
  int nfree;
  {
    unsigned long long f0 = ~ru0;                       // rows 0..63
    unsigned long long f1 = (~ru1) & ((1ull << (NM - 64)) - 1ull);
    int r0 = (int)((f0 >> lane) & 1ull);
    int r1 = (lane < NM - 64) ? (int)((f1 >> lane) & 1ull) : 0;
    if (r0) flist[__popcll(f0 & ((1ull << lane) - 1ull))] = lane;
    int base = (int)__popcll(f0);
    if (r1) flist[base + (int)__popcll(f1 & ((1ull << lane) - 1ull))] = lane + 64;
    nfree = base + (int)__popcll(f1);
  }
  __syncthreads();

  // register mirrors of u[] (p mirrors already current)
  float ur0 = u[lane];
  float ur1 = (lane < NM - 64) ? u[lane + 64] : 0.f;

  // ---- shortest augmenting path (Dijkstra form) for leftover free rows ----
  for (int fi = 0; fi < nfree; ++fi) {
    int i = flist[fi];
    float dv[5]; int usedR[5];
#pragma unroll
    for (int w = 0; w < 5; ++w) {
      int j = lane + 64 * w;
      dv[w] = INF;
      usedR[w] = (j >= NQ) ? 1 : 0;
      way[j] = -1;
    }
    float S = 0.f;
    int nr = i, j0 = -1;
    while (true) {
      float urow;
      {
        int bits = (nr < 64)
            ? __builtin_amdgcn_readlane(__float_as_int(ur0), nr & 63)
            : __builtin_amdgcn_readlane(__float_as_int(ur1), nr & 63);
        urow = __int_as_float(bits);
      }
      int base = nr * CTP;
      float c0 = cost[base + lane];
      float c1 = cost[base + lane + 64];
      float c2_ = cost[base + lane + 128];
      float c3 = cost[base + lane + 192];
      float c4 = cost[base + lane + 256];   // j>=300 lanes: discarded (usedR)
      float cr[5] = {c0, c1, c2_, c3, c4};
      float cmin = INF;
#pragma unroll
      for (int w = 0; w < 5; ++w) {
        if (!usedR[w]) {
          float cand = S + cr[w] - urow - v[w];
          if (cand < dv[w]) { dv[w] = cand; way[lane + 64 * w] = j0; }
          cmin = fminf(cmin, dv[w]);
        }
      }
      float m = wave_fmin_bcast(cmin);
      int j1 = -1;
#pragma unroll
      for (int w = 0; w < 5; ++w) {
        unsigned long long mk = __ballot(!usedR[w] && dv[w] == m);
        if (j1 < 0 && mk) j1 = (int)__builtin_ctzll(mk) + 64 * w;
      }
      S = m;
#pragma unroll
      for (int w = 0; w < 5; ++w) if (lane + 64 * w == j1) usedR[w] = 1;
      j0 = j1;
      int nr2; PREAD(j1, nr2);
      if (nr2 < 0) break;
      nr = nr2;
    }
    // phase-end dual updates (mirror pr* is pre-augmentation p — required)
#pragma unroll
    for (int w = 0; w < 5; ++w) {
      int j = lane + 64 * w;
      if (j < NQ && usedR[w]) {
        float amt = S - dv[w];            // = sum of deltas since j joined
        v[w] -= amt;
        int pj = (w == 0) ? pr0 : (w == 1) ? pr1 : (w == 2) ? pr2
               : (w == 3) ? pr3 : pr4;
        if (pj >= 0) u[pj] += amt;        // distinct rows across lanes
      }
    }
    if (lane == 0) u[i] += S;
    __syncthreads();
    if (lane == 0) {                      // backtrack augmenting path
      int j = j0;
      while (j != -1) {
        int jp = way[j];
        p[j] = (jp != -1) ? p[jp] : i;
        j = jp;
      }
    }
    __syncthreads();
    // refresh mirrors (p rewired by backtrack, u updated above)
    pr0 = p[lane]; pr1 = p[lane + 64]; pr2 = p[lane + 128];
    pr3 = p[lane + 192]; pr4 = p[lane + 256];
    ur0 = u[lane];
    ur1 = (lane < NM - 64) ? u[lane + 64] : 0.f;
  }

  // ---- parallel emit: sorted (pred, gt) pairs via ballot prefix ----
  {
    float* po = out + NB * NQ * NM + b * NM;
    float* go = out + NB * NQ * NM + NB * NM + b * NM;
    int base = 0;
    int prw[5] = {pr0, pr1, pr2, pr3, pr4};
#pragma unroll
    for (int w = 0; w < 5; ++w) {
      int j = lane + 64 * w;
      int pj = (j < NQ) ? prw[w] : -1;
      unsigned long long mask = __ballot(pj >= 0);
      if (pj >= 0) {
        int pos = base + (int)__popcll(mask & ((1ull << lane) - 1ull));
        po[pos] = (float)j;
        go[pos] = (float)pj;
      }
      base += (int)__popcll(mask);
    }
  }
}

extern "C" void kernel_launch(void* const* d_in, const int* in_sizes, int n_in,
                              void* d_out, int out_size, void* d_ws, size_t ws_size,
                              hipStream_t stream) {
  const float* logits = (const float*)d_in[0];
  const float* pboxes = (const float*)d_in[1];
  const float* pmask  = (const float*)d_in[2];
  const int*   labels = (const int*)d_in[3];
  const float* gboxes = (const float*)d_in[4];
  const float* gmask  = (const float*)d_in[5];
  float* out = (float*)d_out;
  char* ws = (char*)d_ws;

  // ws layout (bytes)
  unsigned short* pm   = (unsigned short*)(ws + 0);          //  78,643,200
  unsigned short* gmb  = (unsigned short*)(ws + 78643200);   //  26,214,400
  float* psum  = (float*)(ws + 104857600);                   //       9,600
  float* gsum  = (float*)(ws + 104867200);                   //       3,200
  float* probs = (float*)(ws + 104870400);                   //     777,600
  float* dotv  = (float*)(ws + 105648000);                   //     960,000
  float* ct    = (float*)(ws + 106608000);                   //     972,800

  hipFuncSetAttribute(reinterpret_cast<const void*>(hungarian_kernel),
                      hipFuncAttributeMaxDynamicSharedMemorySize, 127168);

  hipMemsetAsync(dotv, 0, NB * NQ * NM * sizeof(float), stream);
  hipLaunchKernelGGL(prep_kernel, dim3(NB * NQ + NB * NM), dim3(256), 0, stream,
                     pmask, gmask, pm, gmb, psum, gsum);
  hipLaunchKernelGGL(softmax_kernel, dim3(600), dim3(256), 0, stream, logits, probs);
  hipLaunchKernelGGL(dot_kernel, dim3(19, NB * NKC), dim3(64), 0, stream, pm, gmb, dotv);
  hipLaunchKernelGGL(combine_kernel, dim3((NB * NQ * NM + 255) / 256), dim3(256), 0, stream,
                     dotv, psum, gsum, probs, labels, pboxes, gboxes, out, ct);
  hipLaunchKernelGGL(hungarian_kernel, dim3(NB), dim3(64), 127168, stream, ct, out);
}

// Round 5
// 471.147 us; speedup vs baseline: 1.1661x; 1.1661x over previous
//
#include <hip/hip_runtime.h>

#define HW 16384
#define NQ 300
#define NM 100
#define NB 8
#define NC 81
#define KCH 1024   // K split into 16 chunks
#define NKC 16
#define CTP 304    // padded leading dim for transposed cost

typedef __attribute__((ext_vector_type(8))) short frag8;
typedef __attribute__((ext_vector_type(4))) float float4v;
typedef __attribute__((ext_vector_type(4))) unsigned short ushort4v;

__device__ __forceinline__ unsigned short f2bf(float f) {
  union { float f; unsigned u; } c; c.f = f;
  unsigned r = c.u + 0x7FFFu + ((c.u >> 16) & 1u);
  return (unsigned short)(r >> 16);
}

// ---- gm prep: gt_masks (exact 0/1 f32) -> bf16 + row sums ----
// pm staging is GONE: each pm element is consumed exactly once by dot, so
// sigmoid+cvt happen inline there (saves a 78.6MB write + 78.6MB read).
__global__ __launch_bounds__(256) void gmprep_kernel(
    const float* __restrict__ gmask, unsigned short* __restrict__ gm,
    float* __restrict__ gsum) {
  int row = blockIdx.x;            // 0..799 = b*NM+m
  int t = threadIdx.x;
  const float4v* src = (const float4v*)(gmask + (size_t)row * HW);
  unsigned short* dst = gm + (size_t)row * HW;
  float s = 0.f;
  for (int i = t; i < HW / 4; i += 256) {
    float4v x = src[i];
    s += (x.x + x.y) + (x.z + x.w);
    ushort4v o = { f2bf(x.x), f2bf(x.y), f2bf(x.z), f2bf(x.w) };
    *(ushort4v*)(dst + i * 4) = o;
  }
  for (int off = 32; off > 0; off >>= 1) s += __shfl_xor(s, off, 64);
  __shared__ float red[4];
  int wave = t >> 6, lane = t & 63;
  if (lane == 0) red[wave] = s;
  __syncthreads();
  if (t == 0) gsum[row] = (red[0] + red[1]) + (red[2] + red[3]);
}

// ---- softmax over 81 classes, one wave per (b,q) row ----
__global__ __launch_bounds__(256) void softmax_kernel(
    const float* __restrict__ logits, float* __restrict__ probs) {
  int wave = threadIdx.x >> 6, lane = threadIdx.x & 63;
  int row = blockIdx.x * 4 + wave;          // < 2400 (grid=600)
  const float* in = logits + (size_t)row * NC;
  float x0 = (lane < NC) ? in[lane] : -1e30f;
  float x1 = (lane + 64 < NC) ? in[lane + 64] : -1e30f;
  float mx = fmaxf(x0, x1);
  for (int off = 32; off > 0; off >>= 1) mx = fmaxf(mx, __shfl_xor(mx, off, 64));
  float e0 = (lane < NC) ? __expf(x0 - mx) : 0.f;
  float e1 = (lane + 64 < NC) ? __expf(x1 - mx) : 0.f;
  float s = e0 + e1;
  for (int off = 32; off > 0; off >>= 1) s += __shfl_xor(s, off, 64);
  float inv = 1.f / s;
  if (lane < NC) probs[(size_t)row * NC + lane] = e0 * inv;
  if (lane + 64 < NC) probs[(size_t)row * NC + lane + 64] = e1 * inv;
}

// ---- fused bf16 MFMA batched GEMM: sigmoid(pmask f32) inline -> bf16 A,
//      dot[b,q,m] via fp32 atomics, psum[b,q] via one atomic/lane ----
__global__ __launch_bounds__(64) void dot_kernel(
    const float* __restrict__ pmask, const unsigned short* __restrict__ gm,
    float* __restrict__ dotv, float* __restrict__ psum) {
  int qt = blockIdx.x;                      // 0..18 (16-q tiles)
  int b = blockIdx.y >> 4, kc = blockIdx.y & 15;
  int lane = threadIdx.x;
  int q0 = qt * 16;
  int row_a = q0 + (lane & 15);
  int ra = (row_a < NQ) ? row_a : NQ - 1;   // clamp; clamped rows never stored
  int koff = (lane >> 4) * 8;
  const float* pA = pmask + ((size_t)b * NQ + ra) * HW + kc * KCH + koff;
  const unsigned short* pB0 = gm + (size_t)b * NM * HW + kc * KCH + koff;
  const unsigned short* pB[7];
#pragma unroll
  for (int mt = 0; mt < 7; ++mt) {
    int row_b = mt * 16 + (lane & 15);
    int rb = (row_b < NM) ? row_b : NM - 1;
    pB[mt] = pB0 + (size_t)rb * HW;
  }
  float4v acc[7];
#pragma unroll
  for (int mt = 0; mt < 7; ++mt) acc[mt] = (float4v){0.f, 0.f, 0.f, 0.f};
  float asum = 0.f;
#pragma unroll 2
  for (int k = 0; k < KCH; k += 32) {
    float4v x0 = *(const float4v*)(pA + k);
    float4v x1 = *(const float4v*)(pA + k + 4);
    float s0 = 1.f / (1.f + __expf(-x0.x));
    float s1 = 1.f / (1.f + __expf(-x0.y));
    float s2 = 1.f / (1.f + __expf(-x0.z));
    float s3 = 1.f / (1.f + __expf(-x0.w));
    float s4 = 1.f / (1.f + __expf(-x1.x));
    float s5 = 1.f / (1.f + __expf(-x1.y));
    float s6 = 1.f / (1.f + __expf(-x1.z));
    float s7 = 1.f / (1.f + __expf(-x1.w));
    asum += ((s0 + s1) + (s2 + s3)) + ((s4 + s5) + (s6 + s7));
    frag8 a;
    a[0] = (short)f2bf(s0); a[1] = (short)f2bf(s1);
    a[2] = (short)f2bf(s2); a[3] = (short)f2bf(s3);
    a[4] = (short)f2bf(s4); a[5] = (short)f2bf(s5);
    a[6] = (short)f2bf(s6); a[7] = (short)f2bf(s7);
#pragma unroll
    for (int mt = 0; mt < 7; ++mt) {
      frag8 bb = *(const frag8*)(pB[mt] + k);
      acc[mt] = __builtin_amdgcn_mfma_f32_16x16x32_bf16(a, bb, acc[mt], 0, 0, 0);
    }
  }
  if (row_a < NQ) unsafeAtomicAdd(&psum[b * NQ + row_a], asum);
  // C/D layout: col = lane&15 (m), row = (lane>>4)*4 + r (q)
#pragma unroll
  for (int mt = 0; mt < 7; ++mt) {
    int cm = mt * 16 + (lane & 15);
    if (cm < NM) {
#pragma unroll
      for (int r = 0; r < 4; ++r) {
        int cq = q0 + (lane >> 4) * 4 + r;
        if (cq < NQ)
          unsafeAtomicAdd(&dotv[((size_t)b * NQ + cq) * NM + cm], acc[mt][r]);
      }
    }
  }
}

// ---- combine all cost terms -> C (d_out) and transposed copy CT (ws) ----
__global__ __launch_bounds__(256) void combine_kernel(
    const float* __restrict__ dotv, const float* __restrict__ psum,
    const float* __restrict__ gsum, const float* __restrict__ probs,
    const int* __restrict__ labels, const float* __restrict__ pboxes,
    const float* __restrict__ gboxes, float* __restrict__ outC,
    float* __restrict__ ct) {
  int idx = blockIdx.x * 256 + threadIdx.x;
  if (idx >= NB * NQ * NM) return;
  int b = idx / (NQ * NM);
  int r = idx - b * (NQ * NM);
  int q = r / NM;
  int m = r - q * NM;
  float num = 2.f * dotv[idx];
  float den = psum[b * NQ + q] + gsum[b * NM + m];
  float cmask = 1.f - num / (den + 1e-6f);
  int lab = labels[b * NM + m];
  float cclass = -probs[((size_t)b * NQ + q) * NC + lab];
  const float* pb = pboxes + ((size_t)b * NQ + q) * 4;
  const float* gb = gboxes + ((size_t)b * NM + m) * 4;
  float p0 = pb[0], p1 = pb[1], p2 = pb[2], p3 = pb[3];
  float g0 = gb[0], g1 = gb[1], g2 = gb[2], g3 = gb[3];
  float cbbox = fabsf(p0 - g0) + fabsf(p1 - g1) + fabsf(p2 - g2) + fabsf(p3 - g3);
  float iw = fmaxf(fminf(p2, g2) - fmaxf(p0, g0), 0.f);
  float ih = fmaxf(fminf(p3, g3) - fmaxf(p1, g1), 0.f);
  float inter = iw * ih;
  float a1 = (p2 - p0) * (p3 - p1), a2 = (g2 - g0) * (g3 - g1);
  float uni = a1 + a2 - inter;
  float iou = inter / (uni + 1e-6f);
  float aw = fmaxf(fmaxf(p2, g2) - fminf(p0, g0), 0.f);
  float ah = fmaxf(fmaxf(p3, g3) - fminf(p1, g1), 0.f);
  float am = aw * ah;
  float giou = iou - (am - uni) / (am + 1e-6f);
  float C = cclass + 5.f * (cbbox - giou) + 2.f * cmask;
  outC[idx] = C;
  ct[((size_t)b * NM + m) * CTP + q] = C;   // transposed for the solver
}

// f32 full-wave min via DPP (row_shr 1/2/4/8 + bcast15/31 -> lane 63),
// broadcast back through an SGPR. ~6 dependent VALU ops + 1 readlane.
__device__ __forceinline__ float wave_fmin_bcast(float x) {
  int t;
  t = __builtin_amdgcn_update_dpp(__float_as_int(x), __float_as_int(x), 0x111, 0xf, 0xf, false);
  x = fminf(x, __int_as_float(t));  // row_shr:1
  t = __builtin_amdgcn_update_dpp(__float_as_int(x), __float_as_int(x), 0x112, 0xf, 0xf, false);
  x = fminf(x, __int_as_float(t));  // row_shr:2
  t = __builtin_amdgcn_update_dpp(__float_as_int(x), __float_as_int(x), 0x114, 0xf, 0xf, false);
  x = fminf(x, __int_as_float(t));  // row_shr:4
  t = __builtin_amdgcn_update_dpp(__float_as_int(x), __float_as_int(x), 0x118, 0xf, 0xf, false);
  x = fminf(x, __int_as_float(t));  // row_shr:8
  t = __builtin_amdgcn_update_dpp(__float_as_int(x), __float_as_int(x), 0x142, 0xf, 0xf, false);
  x = fminf(x, __int_as_float(t));  // row_bcast:15
  t = __builtin_amdgcn_update_dpp(__float_as_int(x), __float_as_int(x), 0x143, 0xf, 0xf, false);
  x = fminf(x, __int_as_float(t));  // row_bcast:31
  return __int_as_float(__builtin_amdgcn_readlane(__float_as_int(x), 63));
}

// ---- Jonker-Volgenant on cost.T [100 x 300], one wave per batch ----
// EXACT v3 (R2 kernel, measured 127.8us, passed): greedy init + budgeted
// ARR + Dijkstra-form SAP with p/u register mirrors and DPP reduces.
// v4/v5's register-resident ARR + rotated row-reduce regressed ~54us for
// reasons not yet isolated -> reverted wholesale (one change per round).
extern __shared__ char hsmem[];
__global__ __launch_bounds__(64) void hungarian_kernel(
    const float* __restrict__ ct, float* __restrict__ out) {
  float* cost   = (float*)hsmem;                     // 100*304 f32 = 121600 B
  float* u      = (float*)(hsmem + 121600);          // 100 f32
  int*   p      = (int*)(hsmem + 122000);            // 320 int (col -> row)
  int*   way    = (int*)(hsmem + 123280);            // 320 int
  int*   colOwn = (int*)(hsmem + 124560);            // 320 int (reused: flist)
  int*   queue  = (int*)(hsmem + 125840);            // 400 int
  int*   qmisc  = (int*)(hsmem + 127440);            // 8 int: [0]=head [1]=tail
  int*   flist  = colOwn;                            // free-row list (<=100)
  const int b = blockIdx.x;
  const int lane = threadIdx.x;
  const float INF = __builtin_inff();

  // vectorized cost load: 121600 B as float4 (CTP=304 keeps rows 16B-aligned)
  {
    const float4v* a4 = (const float4v*)(ct + (size_t)b * NM * CTP);
    float4v* c4 = (float4v*)cost;
    for (int i = lane; i < NM * CTP / 4; i += 64) c4[i] = a4[i];
  }
#pragma unroll
  for (int w = 0; w < 5; ++w) {
    p[lane + 64 * w] = -1;
    colOwn[lane + 64 * w] = 0x7fffffff;
  }
  if (lane == 0) { qmisc[0] = 0; qmisc[1] = 0; }
  float v[5];
#pragma unroll
  for (int w = 0; w < 5; ++w) v[w] = 0.f;
  __syncthreads();

  // ---- row reduction: u[i] = min_j cost[i][j], colA = first argmin col ----
  int rarg0 = 0, rarg1 = 0;
  {
    int i = lane;                 // rows 0..63
    float mv = INF; int cj = 0;
    for (int j = 0; j < NQ; ++j) {
      float c = cost[i * CTP + j];
      if (c < mv) { mv = c; cj = j; }
    }
    u[i] = mv; rarg0 = cj;
  }
  if (lane < NM - 64) {           // rows 64..99
    int i = lane + 64;
    float mv = INF; int cj = 0;
    for (int j = 0; j < NQ; ++j) {
      float c = cost[i * CTP + j];
      if (c < mv) { mv = c; cj = j; }
    }
    u[i] = mv; rarg1 = cj;
  }
  // ---- parallel greedy: lowest row index wins its argmin column ----
  atomicMin(&colOwn[rarg0], lane);
  if (lane < NM - 64) atomicMin(&colOwn[rarg1], lane + 64);
  __syncthreads();
  int free0 = 0, free1 = 0;
  {
    bool won = (colOwn[rarg0] == lane);
    if (won) p[rarg0] = lane;
    if (lane < NM) {} // no-op
    free0 = won ? 0 : 1;
  }
  int rowUsed0 = free0 ? 0 : 1;
  int rowUsed1 = 0;
  if (lane < NM - 64) {
    bool won = (colOwn[rarg1] == lane + 64);
    if (won) p[rarg1] = lane + 64;
    rowUsed1 = won ? 1 : 0;
    free1 = won ? 0 : 1;
  }
  // rowUsed lives in LDS (queue region precedes it originally; keep LDS array)
  __shared__ int rowUsedA[NM];
  rowUsedA[lane < NM ? lane : 0] = 0;   // init rows 0..63 (lane<64 always <NM)
  rowUsedA[lane] = rowUsed0;
  if (lane < NM - 64) rowUsedA[lane + 64] = rowUsed1;
  // deterministic free-row queue, ascending row index
  {
    unsigned long long m0 = __ballot(free0 != 0);
    if (free0) queue[__popcll(m0 & ((1ull << lane) - 1ull))] = lane;
    int base = (int)__popcll(m0);
    unsigned long long m1 = __ballot(free1 != 0);
    if (free1) queue[base + (int)__popcll(m1 & ((1ull << lane) - 1ull))] = lane + 64;
    base += (int)__popcll(m1);
    if (lane == 0) qmisc[1] = base;
  }

  // ---- augmenting row reduction (budgeted) ----
  int pops = 0;
  while (true) {
    __syncthreads();
    int h = qmisc[0], t = qmisc[1];
    if (h >= t || pops >= 192) break;
    int i = queue[h];
    ++pops;
    if (lane == 0) qmisc[0] = h + 1;
    // wave-parallel scan: keep per-w reduced costs + per-lane min1/min2
    float tv[5];
    float m1 = INF, m2 = INF;
#pragma unroll
    for (int w = 0; w < 5; ++w) {
      int j = lane + 64 * w;
      float tt = (j < NQ) ? (cost[i * CTP + j] - v[w]) : INF;
      tv[w] = tt;
      if (tt < m1) { m2 = m1; m1 = tt; } else if (tt < m2) m2 = tt;
    }
    float m1g = wave_fmin_bcast(m1);
    int j1 = -1;
#pragma unroll
    for (int w = 0; w < 5; ++w) {
      unsigned long long mk = __ballot(tv[w] == m1g);
      if (j1 < 0 && mk) j1 = (int)__builtin_ctzll(mk) + 64 * w;
    }
    // global 2nd min = min over all cols except j1
    float c2c = INF;
#pragma unroll
    for (int w = 0; w < 5; ++w)
      if (lane + 64 * w != j1) c2c = fminf(c2c, tv[w]);
    float c2 = wave_fmin_bcast(c2c);
    float delta = (c2 > m1g) ? (c2 - m1g) : 0.f;
    int i1 = p[j1];
    if (i1 >= 0 && delta <= 0.f) {
      // exact tie on an occupied column: leave row i free for SAP
      if (lane == 0) u[i] = c2;
      continue;
    }
#pragma unroll
    for (int w = 0; w < 5; ++w) if (lane + 64 * w == j1) v[w] -= delta;
    if (lane == 0) {
      u[i] = c2;
      p[j1] = i;
      rowUsedA[i] = 1;
      if (i1 >= 0) { rowUsedA[i1] = 0; queue[t] = i1; qmisc[1] = t + 1; }
    }
  }
  __syncthreads();

  // ---- collect free rows once (SAP never frees an assigned row) ----
  int nfree;
  {
    int r0 = rowUsedA[lane];
    int r1 = (lane < NM - 64) ? rowUsedA[lane + 64] : 1;
    unsigned long long m0 = __ballot(r0 == 0);
    if (!r0) flist[__popcll(m0 & ((1ull << lane) - 1ull))] = lane;
    int base = (int)__popcll(m0);
    unsigned long long m1 = __ballot(r1 == 0);
    if (!r1) flist[base + (int)__popcll(m1 & ((1ull << lane) - 1ull))] = lane + 64;
    nfree = base + (int)__popcll(m1);
  }
  __syncthreads();

  // register mirrors of p[] and u[] (valid while frozen within a SAP phase)
  int pr0, pr1, pr2, pr3, pr4;
  float ur0, ur1;
  pr0 = p[lane]; pr1 = p[lane + 64]; pr2 = p[lane + 128];
  pr3 = p[lane + 192]; pr4 = p[lane + 256];
  ur0 = u[lane];
  ur1 = (lane < NM - 64) ? u[lane + 64] : 0.f;

  // ---- shortest augmenting path (Dijkstra form) for leftover free rows ----
  for (int fi = 0; fi < nfree; ++fi) {
    int i = flist[fi];
    float dv[5]; int usedR[5];
#pragma unroll
    for (int w = 0; w < 5; ++w) {
      int j = lane + 64 * w;
      dv[w] = INF;
      usedR[w] = (j >= NQ) ? 1 : 0;
      way[j] = -1;
    }
    float S = 0.f;
    int nr = i, j0 = -1;
    while (true) {
      float urow;
      {
        int bits = (nr < 64)
            ? __builtin_amdgcn_readlane(__float_as_int(ur0), nr & 63)
            : __builtin_amdgcn_readlane(__float_as_int(ur1), nr & 63);
        urow = __int_as_float(bits);
      }
      int base = nr * CTP;
      float c0 = cost[base + lane];
      float c1 = cost[base + lane + 64];
      float c2_ = cost[base + lane + 128];
      float c3 = cost[base + lane + 192];
      float c4 = cost[base + lane + 256];   // j>=300 lanes: discarded (usedR)
      float cr[5] = {c0, c1, c2_, c3, c4};
      float cmin = INF;
#pragma unroll
      for (int w = 0; w < 5; ++w) {
        if (!usedR[w]) {
          float cand = S + cr[w] - urow - v[w];
          if (cand < dv[w]) { dv[w] = cand; way[lane + 64 * w] = j0; }
          cmin = fminf(cmin, dv[w]);
        }
      }
      float m = wave_fmin_bcast(cmin);
      int j1 = -1;
#pragma unroll
      for (int w = 0; w < 5; ++w) {
        unsigned long long mk = __ballot(!usedR[w] && dv[w] == m);
        if (j1 < 0 && mk) j1 = (int)__builtin_ctzll(mk) + 64 * w;
      }
      S = m;
#pragma unroll
      for (int w = 0; w < 5; ++w) if (lane + 64 * w == j1) usedR[w] = 1;
      j0 = j1;
      // p[j1] via readlane from mirror (uniform j1; p frozen in-phase)
      int nr2;
      {
        int sl = j1 >> 6, ln = j1 & 63;
        if (sl == 0)      nr2 = __builtin_amdgcn_readlane(pr0, ln);
        else if (sl == 1) nr2 = __builtin_amdgcn_readlane(pr1, ln);
        else if (sl == 2) nr2 = __builtin_amdgcn_readlane(pr2, ln);
        else if (sl == 3) nr2 = __builtin_amdgcn_readlane(pr3, ln);
        else              nr2 = __builtin_amdgcn_readlane(pr4, ln);
      }
      if (nr2 < 0) break;
      nr = nr2;
    }
    // phase-end dual updates (mirror pr* is pre-augmentation p — required)
#pragma unroll
    for (int w = 0; w < 5; ++w) {
      int j = lane + 64 * w;
      if (j < NQ && usedR[w]) {
        float amt = S - dv[w];            // = sum of deltas since j joined
        v[w] -= amt;
        int pj = (w == 0) ? pr0 : (w == 1) ? pr1 : (w == 2) ? pr2
               : (w == 3) ? pr3 : pr4;
        if (pj >= 0) u[pj] += amt;        // distinct rows across lanes
      }
    }
    if (lane == 0) u[i] += S;
    __syncthreads();
    if (lane == 0) {                      // backtrack augmenting path
      int j = j0;
      while (j != -1) {
        int jp = way[j];
        p[j] = (jp != -1) ? p[jp] : i;
        j = jp;
      }
    }
    __syncthreads();
    // refresh mirrors (p rewired by backtrack, u updated above)
    pr0 = p[lane]; pr1 = p[lane + 64]; pr2 = p[lane + 128];
    pr3 = p[lane + 192]; pr4 = p[lane + 256];
    ur0 = u[lane];
    ur1 = (lane < NM - 64) ? u[lane + 64] : 0.f;
  }

  // ---- parallel emit: sorted (pred, gt) pairs via ballot prefix ----
  {
    float* po = out + NB * NQ * NM + b * NM;
    float* go = out + NB * NQ * NM + NB * NM + b * NM;
    int base = 0;
    int prw[5] = {pr0, pr1, pr2, pr3, pr4};
#pragma unroll
    for (int w = 0; w < 5; ++w) {
      int j = lane + 64 * w;
      int pj = (j < NQ) ? prw[w] : -1;
      unsigned long long mask = __ballot(pj >= 0);
      if (pj >= 0) {
        int pos = base + (int)__popcll(mask & ((1ull << lane) - 1ull));
        po[pos] = (float)j;
        go[pos] = (float)pj;
      }
      base += (int)__popcll(mask);
    }
  }
}

extern "C" void kernel_launch(void* const* d_in, const int* in_sizes, int n_in,
                              void* d_out, int out_size, void* d_ws, size_t ws_size,
                              hipStream_t stream) {
  const float* logits = (const float*)d_in[0];
  const float* pboxes = (const float*)d_in[1];
  const float* pmask  = (const float*)d_in[2];
  const int*   labels = (const int*)d_in[3];
  const float* gboxes = (const float*)d_in[4];
  const float* gmask  = (const float*)d_in[5];
  float* out = (float*)d_out;
  char* ws = (char*)d_ws;

  // ws layout (bytes) — pm staging eliminated
  unsigned short* gmb  = (unsigned short*)(ws + 0);          //  26,214,400
  float* dotv  = (float*)(ws + 26214400);                    //     960,000
  float* psum  = (float*)(ws + 27174400);                    //       9,600  (contiguous after dotv)
  float* gsum  = (float*)(ws + 27184000);                    //       3,200
  float* probs = (float*)(ws + 27187200);                    //     777,600
  float* ct    = (float*)(ws + 27964800);                    //     972,800

  hipFuncSetAttribute(reinterpret_cast<const void*>(hungarian_kernel),
                      hipFuncAttributeMaxDynamicSharedMemorySize, 127472);

  // zero dotv + psum in one memset (contiguous)
  hipMemsetAsync(dotv, 0, NB * NQ * NM * sizeof(float) + NB * NQ * sizeof(float), stream);
  hipLaunchKernelGGL(gmprep_kernel, dim3(NB * NM), dim3(256), 0, stream,
                     gmask, gmb, gsum);
  hipLaunchKernelGGL(softmax_kernel, dim3(600), dim3(256), 0, stream, logits, probs);
  hipLaunchKernelGGL(dot_kernel, dim3(19, NB * NKC), dim3(64), 0, stream,
                     pmask, gmb, dotv, psum);
  hipLaunchKernelGGL(combine_kernel, dim3((NB * NQ * NM + 255) / 256), dim3(256), 0, stream,
                     dotv, psum, gsum, probs, labels, pboxes, gboxes, out, ct);
  hipLaunchKernelGGL(hungarian_kernel, dim3(NB), dim3(64), 127472, stream, ct, out);
}